// Round 3
// baseline (404.105 us; speedup 1.0000x reference)
//
#include <hip/hip_runtime.h>

// NNLS via normal equations + FISTA.
// Phase 1: M = U^T U, U = [X | y | 1] (2e6 x 37). 8x8 per-lane patches,
//          4 teams/wave. ROUND 3: depth-2 software pipeline — 3 rotating LDS
//          buffers, global_load_lds DMA issued TWO tiles ahead, per-step
//          s_waitcnt vmcnt(W) (counted, never 0 mid-loop) + raw s_barrier.
//          Loads get a ~2-step HBM service window; no per-step drain stall.
//          Buffer = [X 64x32 | Y 64x4] (2304 floats) so one rotating base
//          serves both. XOR chunk swizzle (slot = chunk ^ (row&7)) applied on
//          BOTH the DMA source address and the read side (involution) ->
//          <=2-way LDS conflicts (free). Read offsets precomputed per rs.
//          Grid 1024 = 4 blocks/CU.
// Phase 1b: atomic-free coalesced reduction of per-block partials (transposed
//           layout) into the 40x40 Gram, one block per entry.
// Phase 2: power iteration (8) + FISTA (32); LDS-broadcast matvec, one wave
//          per output column. kappa(G)~1.016 -> fp32-converged well before 32.
//
// NOTE (rounds 1-2 counters): ~306 us of the ~400 us total is the harness's
// 2x 1GB workspace poison fill inside the timed region. Kernel portion is
// ~83-97 us vs a ~62 us floor (gram HBM floor 46 us).

#define NROWS 2000000
#define TR 64                 // tile rows
#define NT (NROWS / TR)       // 31250 tiles, exact
#define GB 1024               // gram blocks (4 blocks/CU)
#define PITERS 8
#define QPITERS 32

#define BUFSZ 2304            // floats per buffer: X [64][32] + Y [64][4]
#define YOFF 2048             // Y region offset within a buffer

__device__ __forceinline__ void lds_dma16(const float* g, float* l) {
  // 16B per lane, LDS dest = wave-uniform base + lane*16
  __builtin_amdgcn_global_load_lds((const __attribute__((address_space(1))) void*)g,
                                   (__attribute__((address_space(3))) void*)l,
                                   16, 0, 0);
}

// u-row layout: [x0..x31 | y0..y3 | 1 | 0 0 0] = cols 0..39
__global__ __launch_bounds__(256) void gram_kernel(const float* __restrict__ X,
                                                   const float* __restrict__ Yg,
                                                   float* __restrict__ Pw) {
  __shared__ float sm[3 * BUFSZ];  // 27.6 KB; epilogue overlays 3840 floats
  const int tid  = threadIdx.x;
  const int lane = tid & 63;
  const int wv   = tid >> 6;
  const int team = lane >> 4;   // 4 teams of 16 lanes
  const int p    = lane & 15;   // patch id; 15 active

  // patch p -> (PI,PJ) in upper triangle of the 5x5 grid of 8x8 col-blocks
  int pp = (p < 15) ? p : 0;
  int PI = 0, rem = pp;
  while (rem >= 5 - PI) { rem -= 5 - PI; ++PI; }
  const int PJ = PI + rem;
  const int PI2 = PI * 2, PJ2 = PJ * 2;
  const bool aX = (PI < 4);     // a-fragment comes from Xbuf (else y/ones)
  const bool bX = (PJ < 4);

  // DMA source addressing (pre-swizzled involution): lane l covers LDS slot
  // l*16 of its segment; slot s = l&7 holds content chunk c = s ^ (row&7),
  // row&7 == l>>3 within every 8-row segment.
  const int drow = lane >> 3;
  const int dc   = ((lane & 7) ^ drow) * 4;
  const float* gx0 = X  + (size_t)((size_t)blockIdx.x * TR + (wv * 2 + 0) * 8 + drow) * 32 + dc;
  const float* gx1 = X  + (size_t)((size_t)blockIdx.x * TR + (wv * 2 + 1) * 8 + drow) * 32 + dc;
  const float* gy  = Yg + (size_t)((size_t)blockIdx.x * TR + lane) * 4;
  const size_t xstride = (size_t)GB * TR * 32;
  const size_t ystride = (size_t)GB * TR * 4;
  const int seg0 = (wv * 2 + 0) * 256;
  const int seg1 = (wv * 2 + 1) * 256;

  // per-rs read offsets (buffer-relative float indices), precomputed
  const int rbase = wv * 16 + team;
  int ra0[4], ra1[4], rb0[4], rb1[4];
#pragma unroll
  for (int rs = 0; rs < 4; ++rs) {
    const int r = rbase + rs * 4;
    const int e = r & 7;
    ra0[rs] = aX ? r * 32 + ((PI2    ) ^ e) * 4 : YOFF + r * 4;
    ra1[rs] = aX ? r * 32 + ((PI2 | 1) ^ e) * 4 : YOFF + r * 4;
    rb0[rs] = bX ? r * 32 + ((PJ2    ) ^ e) * 4 : YOFF + r * 4;
    rb1[rs] = bX ? r * 32 + ((PJ2 | 1) ^ e) * 4 : YOFF + r * 4;
  }

  float acc[8][8];
#pragma unroll
  for (int a = 0; a < 8; ++a)
#pragma unroll
    for (int b = 0; b < 8; ++b) acc[a][b] = 0.f;

  const float4 onesfrag = make_float4(1.f, 0.f, 0.f, 0.f);

  // prologue: DMA tile k=0 into buf0, tile k=1 into buf1 (both always exist:
  // every block runs >= 30 steps)
  lds_dma16(gx0, &sm[0 + seg0]);
  lds_dma16(gx1, &sm[0 + seg1]);
  if (wv == 0) lds_dma16(gy, &sm[0 + YOFF]);
  lds_dma16(gx0 + xstride, &sm[BUFSZ + seg0]);
  lds_dma16(gx1 + xstride, &sm[BUFSZ + seg1]);
  if (wv == 0) lds_dma16(gy + ystride, &sm[BUFSZ + YOFF]);
  gx0 += 2 * xstride; gx1 += 2 * xstride; gy += 2 * ystride;

  int bc = 0, bn = BUFSZ, bf = 2 * BUFSZ;  // current / next / fill-target
  int tile = blockIdx.x;
  while (tile < NT) {
    // wait: my batch for `tile` complete; batch for tile+GB may stay in flight
    if (tile + GB < NT) {
      if (wv == 0) asm volatile("s_waitcnt vmcnt(3)" ::: "memory");
      else         asm volatile("s_waitcnt vmcnt(2)" ::: "memory");
    } else {
      asm volatile("s_waitcnt vmcnt(0)" ::: "memory");
    }
    __builtin_amdgcn_sched_barrier(0);
    __builtin_amdgcn_s_barrier();   // all waves' batch(tile) done; readers of
    __builtin_amdgcn_sched_barrier(0);  // buffer bf finished last step

    const int nt2 = tile + 2 * GB;
    if (nt2 < NT) {  // DMA tile+2 into the buffer freed at this barrier
      lds_dma16(gx0, &sm[bf + seg0]);
      lds_dma16(gx1, &sm[bf + seg1]);
      if (wv == 0) lds_dma16(gy, &sm[bf + YOFF]);
      gx0 += xstride; gx1 += xstride; gy += ystride;
    }

#pragma unroll
    for (int rs = 0; rs < 4; ++rs) {
      float4 a0 = *(const float4*)&sm[bc + ra0[rs]];
      float4 a1 = *(const float4*)&sm[bc + ra1[rs]];
      float4 b0 = *(const float4*)&sm[bc + rb0[rs]];
      float4 b1 = *(const float4*)&sm[bc + rb1[rs]];
      if (!aX) a1 = onesfrag;   // u[36..39] = [1,0,0,0]
      if (!bX) b1 = onesfrag;
      float av[8] = {a0.x, a0.y, a0.z, a0.w, a1.x, a1.y, a1.z, a1.w};
      float bv[8] = {b0.x, b0.y, b0.z, b0.w, b1.x, b1.y, b1.z, b1.w};
#pragma unroll
      for (int a = 0; a < 8; ++a)
#pragma unroll
        for (int b = 0; b < 8; ++b) acc[a][b] = fmaf(av[a], bv[b], acc[a][b]);
    }

    const int t = bc; bc = bn; bn = bf; bf = t;  // rotate buffers
    tile += GB;
  }

  // cross-team reduce (lane bits 4,5), then transposed partial store:
  // Pw[e*GB + block] -> reduce_kernel reads coalesced
#pragma unroll
  for (int a = 0; a < 8; ++a)
#pragma unroll
    for (int b = 0; b < 8; ++b) {
      float v = acc[a][b];
      v += __shfl_xor(v, 16);
      v += __shfl_xor(v, 32);
      acc[a][b] = v;
    }
  __syncthreads();
  if (p < 15 && team == 0) {
#pragma unroll
    for (int a = 0; a < 8; ++a)
#pragma unroll
      for (int b = 0; b < 8; ++b)
        sm[wv * 960 + p * 64 + a * 8 + b] = acc[a][b];
  }
  __syncthreads();
  for (int e = tid; e < 960; e += 256)
    Pw[(size_t)e * GB + blockIdx.x] = sm[e] + sm[e + 960] + sm[e + 1920] + sm[e + 2880];
}

// One block per Gram entry; coalesced fold of GB partials; scatter into 40x40.
__global__ __launch_bounds__(256) void reduce_kernel(const float* __restrict__ Pw,
                                                     float* __restrict__ Mw) {
  __shared__ float red[4];
  const int t   = blockIdx.x;       // entry 0..959
  const int tid = threadIdx.x;
  float s = 0.f;
#pragma unroll
  for (int k = 0; k < GB / 256; ++k) s += Pw[(size_t)t * GB + k * 256 + tid];
#pragma unroll
  for (int off = 32; off; off >>= 1) s += __shfl_xor(s, off);
  if ((tid & 63) == 0) red[tid >> 6] = s;
  __syncthreads();
  if (tid == 0) {
    float sum = red[0] + red[1] + red[2] + red[3];
    int pe = t >> 6, idx = t & 63;
    int bi = 0, r2 = pe;
    while (r2 >= 5 - bi) { r2 -= 5 - bi; ++bi; }
    const int bj = bi + r2;
    Mw[(bi * 8 + (idx >> 3)) * 40 + (bj * 8 + (idx & 7))] = sum;
  }
}

// dot of 36-float register row with 36-float LDS vector (uniform addr = broadcast)
__device__ __forceinline__ float dot36(const float* __restrict__ Gr, const float4* __restrict__ y4) {
  float g0 = 0.f, g1 = 0.f, g2 = 0.f, g3 = 0.f;
#pragma unroll
  for (int c = 0; c < 9; ++c) {
    float4 y = y4[c];
    g0 = fmaf(Gr[c * 4 + 0], y.x, g0);
    g1 = fmaf(Gr[c * 4 + 1], y.y, g1);
    g2 = fmaf(Gr[c * 4 + 2], y.z, g2);
    g3 = fmaf(Gr[c * 4 + 3], y.w, g3);
  }
  return (g0 + g1) + (g2 + g3);
}

__device__ __forceinline__ float wave_sum(float x) {
#pragma unroll
  for (int off = 32; off; off >>= 1) x += __shfl_xor(x, off);
  return x;
}

// A-col a in [0,33): U(a) = a<32 ? a : 36. c columns = u-cols 32..35.
// M holds upper 8x8 blocks only: mirror via (Ui>>3) vs (Uk>>3).
__global__ __launch_bounds__(256) void solve_kernel(const float* __restrict__ Mw,
                                                    float* __restrict__ out) {
  __shared__ float4 Yb4[2][4][9];
  const int tid  = threadIdx.x;
  const int lane = tid & 63;
  const int col  = tid >> 6;       // one wave per output column
  const bool act = lane < 33;
  const int i  = act ? lane : 0;
  const int Ui = (i < 32) ? i : 36;

  float Gr[36];
#pragma unroll
  for (int k = 0; k < 33; ++k) {
    const int Uk = (k < 32) ? k : 36;
    Gr[k] = ((Ui >> 3) <= (Uk >> 3)) ? Mw[Ui * 40 + Uk] : Mw[Uk * 40 + Ui];
  }
  Gr[33] = Gr[34] = Gr[35] = 0.f;
  const float ci = Mw[Ui * 40 + 32 + col];

  if (lane < 9) {
    Yb4[0][col][lane] = make_float4(0.f, 0.f, 0.f, 0.f);
    Yb4[1][col][lane] = make_float4(0.f, 0.f, 0.f, 0.f);
  }
  __syncthreads();
  float v = rsqrtf(33.f);
  if (act) ((float*)&Yb4[0][col][0])[i] = v;
  __syncthreads();

  // power iteration for step; Rayleigh quotient <= lambda_max, so step >= 1/L;
  // any step in (0, 2/L) converges to the same QP fixed point (kappa ~ 1.016)
  for (int it = 0; it < PITERS; ++it) {
    const int rb = it & 1;
    float w = dot36(Gr, &Yb4[rb][col][0]);
    float x = wave_sum(act ? w * w : 0.f);
    float vn = w * rsqrtf(x);
    if (act) ((float*)&Yb4[rb ^ 1][col][0])[i] = vn;
    v = vn;
    __syncthreads();
  }
  {
    const int rb = PITERS & 1;
    float w = dot36(Gr, &Yb4[rb][col][0]);
    v = wave_sum(act ? v * w : 0.f);  // v^T G v
  }
  const float step = 1.f / v;

  __syncthreads();
  if (act) ((float*)&Yb4[0][col][0])[i] = 0.f;
  __syncthreads();

  float Z = 0.f, Yv = 0.f, t = 1.f;
  for (int it = 0; it < QPITERS; ++it) {
    const int rb = it & 1;
    float g = dot36(Gr, &Yb4[rb][col][0]);
    float zn = Yv - step * (g - ci);
    if (lane < 32) zn = fmaxf(zn, 0.f);  // W rows clamped; bias row free
    float tn = 0.5f * (1.f + sqrtf(fmaf(4.f * t, t, 1.f)));
    float beta = (t - 1.f) / tn;
    float yn = fmaf(beta, zn - Z, zn);
    if (act) ((float*)&Yb4[rb ^ 1][col][0])[i] = yn;
    Z = zn; Yv = yn; t = tn;
    __syncthreads();
  }
  if (lane < 32) out[lane * 4 + col] = Z;  // W is [32,4] row-major
}

extern "C" void kernel_launch(void* const* d_in, const int* in_sizes, int n_in,
                              void* d_out, int out_size, void* d_ws, size_t ws_size,
                              hipStream_t stream) {
  const float* X  = (const float*)d_in[0];
  const float* Yg = (const float*)d_in[1];
  float* Pw  = (float*)d_ws;                 // 960*GB floats of partials (transposed)
  float* Mw  = Pw + (size_t)960 * GB;        // 40x40 Gram (upper blocks)
  float* out = (float*)d_out;

  hipLaunchKernelGGL(gram_kernel,   dim3(GB),  dim3(256), 0, stream, X, Yg, Pw);
  hipLaunchKernelGGL(reduce_kernel, dim3(960), dim3(256), 0, stream, Pw, Mw);
  hipLaunchKernelGGL(solve_kernel,  dim3(1),   dim3(256), 0, stream, Mw, out);
}

// Round 4
// 392.725 us; speedup vs baseline: 1.0290x; 1.0290x over previous
//
#include <hip/hip_runtime.h>

// NNLS via normal equations + FISTA.
// Phase 1: M = U^T U, U = [X | y | 1] (2e6 x 37). ROUND 4: BARRIER-FREE gram.
//          Key insight: wave wv only reads rows [wv*16, wv*16+16) of each
//          tile, so the 4 waves are independent sub-problems. Each wave
//          stages its OWN 16-row band into its OWN LDS region (X [16][36]
//          pad-36 additive bank spread + y [16][4]), register prefetch one
//          tile ahead. Intra-wave LDS write->read needs NO barrier (DS pipe
//          is in-order per wave); prefetch wait is a per-wave vmcnt on a
//          true dependency. 16 free-running waves/CU hide HBM latency by
//          TLP; zero __syncthreads in the main loop (2 remain in epilogue).
//          Grid 1024 = 4 blocks/CU, ~15 KB LDS/block.
// Phase 1b: atomic-free coalesced reduction of per-block partials (transposed
//           layout) into the 40x40 Gram, one block per entry.
// Phase 2: power iteration (8) + FISTA (32); LDS-broadcast matvec, one wave
//          per output column. kappa(G)~1.016 -> fp32-converged well before 32.
//
// NOTE (rounds 1-3 counters): ~306 us of the ~400 us total is the harness's
// 2x 1GB workspace poison fill inside the timed region (untouchable).
// Kernel portion: r1 register-staged+barriers ~85 us, r2/r3 DMA-staged
// ~98 us (DMA machinery pure overhead here). Gram HBM floor ~45 us.

#define NROWS 2000000
#define TR 64                 // tile rows
#define NT (NROWS / TR)       // 31250 tiles, exact
#define GB 1024               // gram blocks (4 blocks/CU)
#define PITERS 8
#define QPITERS 32

#define BAND 16               // rows per wave
#define XPAD 36               // padded X row stride (additive (r+c)&7 spread)
#define YOFFW (BAND * XPAD)   // 576: y region within wave buffer
#define WBUF (YOFFW + BAND * 4)  // 640 floats per wave buffer

// u-row layout: [x0..x31 | y0..y3 | 1 | 0 0 0] = cols 0..39
__global__ __launch_bounds__(256) void gram_kernel(const float* __restrict__ X,
                                                   const float* __restrict__ Yg,
                                                   float* __restrict__ Pw) {
  __shared__ float sm[3840];  // 4*WBUF=2560 live in loop; 3840 epilogue overlay
  const int tid  = threadIdx.x;
  const int lane = tid & 63;
  const int wv   = tid >> 6;
  const int team = lane >> 4;   // 4 teams of 16 lanes
  const int p    = lane & 15;   // patch id; 15 active

  // patch p -> (PI,PJ) in upper triangle of the 5x5 grid of 8x8 col-blocks
  int pp = (p < 15) ? p : 0;
  int PI = 0, rem = pp;
  while (rem >= 5 - PI) { rem -= 5 - PI; ++PI; }
  const int PJ = PI + rem;
  const int PI2 = PI * 2, PJ2 = PJ * 2;
  const bool aX = (PI < 4);     // a-fragment from X band (else y/ones)
  const bool bX = (PJ < 4);

  float* myb = &sm[wv * WBUF];  // this wave's private buffer

  // staging: lane covers band rows srow and srow+8, float4 chunk sch
  const int srow = lane >> 3;   // 0..7
  const int sch  = lane & 7;
  const int w0 = srow * XPAD + sch * 4;
  const int w1 = (srow + 8) * XPAD + sch * 4;
  const int wy = YOFFW + lane;  // 1 float/lane covers 16x4 y band
  const float4* X4 = (const float4*)X;

  // per-rs read offsets (band-relative float indices), compile-time indexed
  int ra0[4], ra1[4], rb0[4], rb1[4];
#pragma unroll
  for (int rs = 0; rs < 4; ++rs) {
    const int rloc = team + rs * 4;   // band row 0..15
    ra0[rs] = aX ? rloc * XPAD + (PI2    ) * 4 : YOFFW + rloc * 4;
    ra1[rs] = aX ? rloc * XPAD + (PI2 | 1) * 4 : YOFFW + rloc * 4;
    rb0[rs] = bX ? rloc * XPAD + (PJ2    ) * 4 : YOFFW + rloc * 4;
    rb1[rs] = bX ? rloc * XPAD + (PJ2 | 1) * 4 : YOFFW + rloc * 4;
  }

  float acc[8][8];
#pragma unroll
  for (int a = 0; a < 8; ++a)
#pragma unroll
    for (int b = 0; b < 8; ++b) acc[a][b] = 0.f;

  const float4 onesfrag = make_float4(1.f, 0.f, 0.f, 0.f);

  // prologue: load tile 0 band into registers
  int tile = blockIdx.x;
  float4 v0, v1; float yv;
  {
    const size_t gr = (size_t)tile * TR + wv * BAND;
    v0 = X4[(gr + srow) * 8 + sch];
    v1 = X4[(gr + srow + 8) * 8 + sch];
    yv = Yg[(gr + (lane >> 2)) * 4 + (lane & 3)];
  }

  while (tile < NT) {
    // stage this wave's band (in-order DS per wave: no barrier needed;
    // compiler inserts vmcnt wait for v0/v1/yv and lgkmcnt before reads)
    *(float4*)&myb[w0] = v0;
    *(float4*)&myb[w1] = v1;
    myb[wy] = yv;

    const int nt = tile + GB;
    if (nt < NT) {  // prefetch next tile's band; latency hides under compute
      const size_t gr = (size_t)nt * TR + wv * BAND;
      v0 = X4[(gr + srow) * 8 + sch];
      v1 = X4[(gr + srow + 8) * 8 + sch];
      yv = Yg[(gr + (lane >> 2)) * 4 + (lane & 3)];
    }

#pragma unroll
    for (int rs = 0; rs < 4; ++rs) {
      float4 a0 = *(const float4*)&myb[ra0[rs]];
      float4 a1 = *(const float4*)&myb[ra1[rs]];
      float4 b0 = *(const float4*)&myb[rb0[rs]];
      float4 b1 = *(const float4*)&myb[rb1[rs]];
      if (!aX) a1 = onesfrag;   // u[36..39] = [1,0,0,0]
      if (!bX) b1 = onesfrag;
      float av[8] = {a0.x, a0.y, a0.z, a0.w, a1.x, a1.y, a1.z, a1.w};
      float bv[8] = {b0.x, b0.y, b0.z, b0.w, b1.x, b1.y, b1.z, b1.w};
#pragma unroll
      for (int a = 0; a < 8; ++a)
#pragma unroll
        for (int b = 0; b < 8; ++b) acc[a][b] = fmaf(av[a], bv[b], acc[a][b]);
    }
    tile = nt;
  }

  // cross-team reduce (lane bits 4,5), then transposed partial store:
  // Pw[e*GB + block] -> reduce_kernel reads coalesced
#pragma unroll
  for (int a = 0; a < 8; ++a)
#pragma unroll
    for (int b = 0; b < 8; ++b) {
      float v = acc[a][b];
      v += __shfl_xor(v, 16);
      v += __shfl_xor(v, 32);
      acc[a][b] = v;
    }
  __syncthreads();  // all waves done with private buffers -> overlay reuse
  if (p < 15 && team == 0) {
#pragma unroll
    for (int a = 0; a < 8; ++a)
#pragma unroll
      for (int b = 0; b < 8; ++b)
        sm[wv * 960 + p * 64 + a * 8 + b] = acc[a][b];
  }
  __syncthreads();
  for (int e = tid; e < 960; e += 256)
    Pw[(size_t)e * GB + blockIdx.x] = sm[e] + sm[e + 960] + sm[e + 1920] + sm[e + 2880];
}

// One block per Gram entry; coalesced fold of GB partials; scatter into 40x40.
__global__ __launch_bounds__(256) void reduce_kernel(const float* __restrict__ Pw,
                                                     float* __restrict__ Mw) {
  __shared__ float red[4];
  const int t   = blockIdx.x;       // entry 0..959
  const int tid = threadIdx.x;
  float s = 0.f;
#pragma unroll
  for (int k = 0; k < GB / 256; ++k) s += Pw[(size_t)t * GB + k * 256 + tid];
#pragma unroll
  for (int off = 32; off; off >>= 1) s += __shfl_xor(s, off);
  if ((tid & 63) == 0) red[tid >> 6] = s;
  __syncthreads();
  if (tid == 0) {
    float sum = red[0] + red[1] + red[2] + red[3];
    int pe = t >> 6, idx = t & 63;
    int bi = 0, r2 = pe;
    while (r2 >= 5 - bi) { r2 -= 5 - bi; ++bi; }
    const int bj = bi + r2;
    Mw[(bi * 8 + (idx >> 3)) * 40 + (bj * 8 + (idx & 7))] = sum;
  }
}

// dot of 36-float register row with 36-float LDS vector (uniform addr = broadcast)
__device__ __forceinline__ float dot36(const float* __restrict__ Gr, const float4* __restrict__ y4) {
  float g0 = 0.f, g1 = 0.f, g2 = 0.f, g3 = 0.f;
#pragma unroll
  for (int c = 0; c < 9; ++c) {
    float4 y = y4[c];
    g0 = fmaf(Gr[c * 4 + 0], y.x, g0);
    g1 = fmaf(Gr[c * 4 + 1], y.y, g1);
    g2 = fmaf(Gr[c * 4 + 2], y.z, g2);
    g3 = fmaf(Gr[c * 4 + 3], y.w, g3);
  }
  return (g0 + g1) + (g2 + g3);
}

__device__ __forceinline__ float wave_sum(float x) {
#pragma unroll
  for (int off = 32; off; off >>= 1) x += __shfl_xor(x, off);
  return x;
}

// A-col a in [0,33): U(a) = a<32 ? a : 36. c columns = u-cols 32..35.
// M holds upper 8x8 blocks only: mirror via (Ui>>3) vs (Uk>>3).
__global__ __launch_bounds__(256) void solve_kernel(const float* __restrict__ Mw,
                                                    float* __restrict__ out) {
  __shared__ float4 Yb4[2][4][9];
  const int tid  = threadIdx.x;
  const int lane = tid & 63;
  const int col  = tid >> 6;       // one wave per output column
  const bool act = lane < 33;
  const int i  = act ? lane : 0;
  const int Ui = (i < 32) ? i : 36;

  float Gr[36];
#pragma unroll
  for (int k = 0; k < 33; ++k) {
    const int Uk = (k < 32) ? k : 36;
    Gr[k] = ((Ui >> 3) <= (Uk >> 3)) ? Mw[Ui * 40 + Uk] : Mw[Uk * 40 + Ui];
  }
  Gr[33] = Gr[34] = Gr[35] = 0.f;
  const float ci = Mw[Ui * 40 + 32 + col];

  if (lane < 9) {
    Yb4[0][col][lane] = make_float4(0.f, 0.f, 0.f, 0.f);
    Yb4[1][col][lane] = make_float4(0.f, 0.f, 0.f, 0.f);
  }
  __syncthreads();
  float v = rsqrtf(33.f);
  if (act) ((float*)&Yb4[0][col][0])[i] = v;
  __syncthreads();

  // power iteration for step; Rayleigh quotient <= lambda_max, so step >= 1/L;
  // any step in (0, 2/L) converges to the same QP fixed point (kappa ~ 1.016)
  for (int it = 0; it < PITERS; ++it) {
    const int rb = it & 1;
    float w = dot36(Gr, &Yb4[rb][col][0]);
    float x = wave_sum(act ? w * w : 0.f);
    float vn = w * rsqrtf(x);
    if (act) ((float*)&Yb4[rb ^ 1][col][0])[i] = vn;
    v = vn;
    __syncthreads();
  }
  {
    const int rb = PITERS & 1;
    float w = dot36(Gr, &Yb4[rb][col][0]);
    v = wave_sum(act ? v * w : 0.f);  // v^T G v
  }
  const float step = 1.f / v;

  __syncthreads();
  if (act) ((float*)&Yb4[0][col][0])[i] = 0.f;
  __syncthreads();

  float Z = 0.f, Yv = 0.f, t = 1.f;
  for (int it = 0; it < QPITERS; ++it) {
    const int rb = it & 1;
    float g = dot36(Gr, &Yb4[rb][col][0]);
    float zn = Yv - step * (g - ci);
    if (lane < 32) zn = fmaxf(zn, 0.f);  // W rows clamped; bias row free
    float tn = 0.5f * (1.f + sqrtf(fmaf(4.f * t, t, 1.f)));
    float beta = (t - 1.f) / tn;
    float yn = fmaf(beta, zn - Z, zn);
    if (act) ((float*)&Yb4[rb ^ 1][col][0])[i] = yn;
    Z = zn; Yv = yn; t = tn;
    __syncthreads();
  }
  if (lane < 32) out[lane * 4 + col] = Z;  // W is [32,4] row-major
}

extern "C" void kernel_launch(void* const* d_in, const int* in_sizes, int n_in,
                              void* d_out, int out_size, void* d_ws, size_t ws_size,
                              hipStream_t stream) {
  const float* X  = (const float*)d_in[0];
  const float* Yg = (const float*)d_in[1];
  float* Pw  = (float*)d_ws;                 // 960*GB floats of partials (transposed)
  float* Mw  = Pw + (size_t)960 * GB;        // 40x40 Gram (upper blocks)
  float* out = (float*)d_out;

  hipLaunchKernelGGL(gram_kernel,   dim3(GB),  dim3(256), 0, stream, X, Yg, Pw);
  hipLaunchKernelGGL(reduce_kernel, dim3(960), dim3(256), 0, stream, Pw, Mw);
  hipLaunchKernelGGL(solve_kernel,  dim3(1),   dim3(256), 0, stream, Mw, out);
}